// Round 8
// baseline (130.650 us; speedup 1.0000x reference)
//
#include <hip/hip_runtime.h>

namespace {

constexpr int Cn   = 256;
constexpr int Hh   = 128;
constexpr int Ww   = 128;
constexpr int HW   = Hh * Ww;
constexpr int TW   = 16;              // tile width
constexpr int TH   = 8;               // tile height
constexpr int CCH  = 8;               // channels per LDS chunk
constexpr int NCH  = Cn / CCH;        // 32 chunks
constexpr int HALO = 4;
constexpr int SR   = TH + 2 * HALO;   // 16 staged rows
constexpr int SC   = TW + 2 * HALO;   // 24 staged cols
constexpr int SC4  = SC / 4;          // 6 float4 per staged row
constexpr int SS   = 28;              // padded row stride (floats) = 7 granules (odd)
constexpr int SCH  = SR * SS;         // 448 floats per channel (112 granules, %8==0)
constexpr int NOFF = 81;
constexpr int NF4  = CCH * SR * SC4;  // 768 staged float4 per chunk

// 576 threads = 9 waves; wave wv <-> window row di = wv (o = 9*wv + dj).
// Lane l: h = l&7, m = (l>>3)&1 (px cols 8m..8m+7), c4 = l>>4 (4-way channel
// split, shuffle-reduced at epilogue). h in the low lane bits + odd granule
// stride (7) => conflict-free ds_read_b128. Staging is float4-granular
// (ds_write_b128): round-7's 6.29M conflict cycles were the scalar writes.

__global__ __launch_bounds__(576, 2)   // cap 256 VGPR ((,5) spilled in r6)
void costvol_kernel(const float* __restrict__ x1,
                    const float* __restrict__ x2,
                    float* __restrict__ out)
{
  __shared__ float s2[2][CCH * SCH];   // 28,672 B

  const int t  = threadIdx.x;
  const int wv = t >> 6;               // di = 0..8
  const int l  = t & 63;
  const int h  = l & 7;
  const int m  = (l >> 3) & 1;
  const int c4 = l >> 4;

  const int x0 = blockIdx.x * TW;
  const int y0 = blockIdx.y * TH;
  const int b  = blockIdx.z;

  const float* g1 = x1 + (size_t)b * Cn * HW + (size_t)(y0 + h) * Ww + (x0 + 8 * m);
  const float* g2 = x2 + (size_t)b * Cn * HW;

  // ---- float4-granular staging map: slot j stages float4 f = t + 576*j ----
  // f -> ch = f/96, rem = f%96, row = rem/6, col4 = rem%6.
  // gx = x0-4+4*col4 is 16B-aligned; every granule is fully in- or out-of-range.
  int  soff[2], swr[2];
  bool sval[2], sok[2];
#pragma unroll
  for (int j = 0; j < 2; ++j) {
    const int f    = t + 576 * j;
    const bool okf = (f < NF4);
    const int ch   = f / (SR * SC4);
    const int rem  = f % (SR * SC4);
    const int row  = rem / SC4, col4 = rem % SC4;
    const int gy = y0 - HALO + row;
    const int gx = x0 - HALO + 4 * col4;
    const bool ok = okf && ((unsigned)gy < (unsigned)Hh) && ((unsigned)gx < (unsigned)Ww);
    sok[j]  = okf;
    sval[j] = ok;
    soff[j] = ok ? (ch * HW + gy * Ww + gx) : 0;
    swr[j]  = okf ? (ch * SCH + row * SS + 4 * col4) : 0;
  }

  float4 rs[2];
  auto stage_load = [&](int k) {
    const size_t cb = (size_t)(k * CCH) * HW;
#pragma unroll
    for (int j = 0; j < 2; ++j)
      rs[j] = sval[j] ? *reinterpret_cast<const float4*>(g2 + cb + soff[j])
                      : float4{0.f, 0.f, 0.f, 0.f};
  };
  auto stage_write = [&](int nb) {
    float* s = s2[nb];
#pragma unroll
    for (int j = 0; j < 2; ++j)
      if (sok[j]) *reinterpret_cast<float4*>(s + swr[j]) = rs[j];
  };

  float acc[9][8];
#pragma unroll
  for (int d = 0; d < 9; ++d)
#pragma unroll
    for (int p = 0; p < 8; ++p) acc[d][p] = 0.0f;

  const int rbase = (h + wv) * SS + 8 * m;

  stage_load(0);
  stage_write(0);
  __syncthreads();

  for (int k = 0; k < NCH; ++k) {
    if (k + 1 < NCH) stage_load(k + 1);              // issue early (T14)
    const float* sc_ = s2[k & 1];

    // ---- issue ALL loads for the chunk before any FMA (2-step pipeline) ----
    const size_t c0 = (size_t)(CCH * k + c4) * HW;       // s=0 channel
    const size_t c1 = (size_t)(CCH * k + 4 + c4) * HW;   // s=1 channel
    const float4 a00 = *reinterpret_cast<const float4*>(g1 + c0);
    const float4 a01 = *reinterpret_cast<const float4*>(g1 + c0 + 4);
    const float4 a10 = *reinterpret_cast<const float4*>(g1 + c1);
    const float4 a11 = *reinterpret_cast<const float4*>(g1 + c1 + 4);

    const float* bp0 = sc_ + c4 * SCH + rbase;
    const float* bp1 = sc_ + (4 + c4) * SCH + rbase;
    float w0[16], w1[16];
    *reinterpret_cast<float4*>(w0)      = *reinterpret_cast<const float4*>(bp0);
    *reinterpret_cast<float4*>(w0 + 4)  = *reinterpret_cast<const float4*>(bp0 + 4);
    *reinterpret_cast<float4*>(w0 + 8)  = *reinterpret_cast<const float4*>(bp0 + 8);
    *reinterpret_cast<float4*>(w0 + 12) = *reinterpret_cast<const float4*>(bp0 + 12);
    *reinterpret_cast<float4*>(w1)      = *reinterpret_cast<const float4*>(bp1);
    *reinterpret_cast<float4*>(w1 + 4)  = *reinterpret_cast<const float4*>(bp1 + 4);
    *reinterpret_cast<float4*>(w1 + 8)  = *reinterpret_cast<const float4*>(bp1 + 8);
    *reinterpret_cast<float4*>(w1 + 12) = *reinterpret_cast<const float4*>(bp1 + 12);

    const float av0[8] = {a00.x, a00.y, a00.z, a00.w, a01.x, a01.y, a01.z, a01.w};
#pragma unroll
    for (int dj = 0; dj < 9; ++dj)
#pragma unroll
      for (int p = 0; p < 8; ++p)
        acc[dj][p] = fmaf(av0[p], w0[p + dj], acc[dj][p]);

    const float av1[8] = {a10.x, a10.y, a10.z, a10.w, a11.x, a11.y, a11.z, a11.w};
#pragma unroll
    for (int dj = 0; dj < 9; ++dj)
#pragma unroll
      for (int p = 0; p < 8; ++p)
        acc[dj][p] = fmaf(av1[p], w1[p + dj], acc[dj][p]);

    if (k + 1 < NCH) stage_write((k + 1) & 1);       // write late
    __syncthreads();
  }

  // ---- epilogue: reduce 4-way channel split (lanes l, l+16, l+32, l+48) ----
#pragma unroll
  for (int dj = 0; dj < 9; ++dj)
#pragma unroll
    for (int p = 0; p < 8; ++p) {
      float v = acc[dj][p];
      v += __shfl_down(v, 32);
      v += __shfl_down(v, 16);
      acc[dj][p] = v;
    }

  if (l < 16) {                                      // h = l&7, m = (l>>3)&1
    const float invc = 1.0f / (float)Cn;
    const int y  = y0 + h;
    const int xb = x0 + 8 * m;
#pragma unroll
    for (int dj = 0; dj < 9; ++dj) {
      const int o = wv * 9 + dj;
      float* op = out + (((size_t)b * NOFF + o) * Hh + y) * Ww + xb;
      float4 v0, v1;
      v0.x = acc[dj][0] * invc; v0.y = acc[dj][1] * invc;
      v0.z = acc[dj][2] * invc; v0.w = acc[dj][3] * invc;
      v1.x = acc[dj][4] * invc; v1.y = acc[dj][5] * invc;
      v1.z = acc[dj][6] * invc; v1.w = acc[dj][7] * invc;
      *reinterpret_cast<float4*>(op)     = v0;
      *reinterpret_cast<float4*>(op + 4) = v1;
    }
  }
}

} // namespace

extern "C" void kernel_launch(void* const* d_in, const int* in_sizes, int n_in,
                              void* d_out, int out_size, void* d_ws, size_t ws_size,
                              hipStream_t stream) {
  const float* x1 = (const float*)d_in[0];
  const float* x2 = (const float*)d_in[1];
  float* out = (float*)d_out;

  dim3 grid(Ww / TW, Hh / TH, 4);   // 8 x 16 x 4 = 512 blocks
  dim3 block(576);                  // 9 waves: wave wv <-> window row di
  costvol_kernel<<<grid, block, 0, stream>>>(x1, x2, out);
}

// Round 9
// 120.624 us; speedup vs baseline: 1.0831x; 1.0831x over previous
//
#include <hip/hip_runtime.h>

namespace {

constexpr int Cn   = 256;
constexpr int Hh   = 128;
constexpr int Ww   = 128;
constexpr int HW   = Hh * Ww;
constexpr int TW   = 16;              // tile width
constexpr int TH   = 8;               // tile height
constexpr int CCH  = 8;               // channels per LDS chunk
constexpr int NCH  = Cn / CCH;        // 32 chunks
constexpr int HALO = 4;
constexpr int SRR  = 10;              // staged rows per type: h+w, h<8, w<3
constexpr int SC4  = 6;               // float4 per staged row (24 cols)
constexpr int SS   = 28;              // padded row stride (floats), 7 granules (odd)
constexpr int SCH  = SRR * SS;        // 280 floats per channel
constexpr int NOFF = 81;
constexpr int NF4  = CCH * SRR * SC4; // 480 staged float4 per chunk

// 192 threads = 3 waves. Block type T covers di in {3T, 3T+1, 3T+2};
// wave w <-> di = 3T+w (o = 9*di + dj, each o written by exactly one block).
// Lane l: h = l&7 (tile row), m = (l>>3)&1 (px cols 8m..8m+7), c4 = l>>4
// (4-way channel split, shuffle-reduced at epilogue).
// Small blocks co-reside (~4/CU = 12 waves) so independent blocks overlap
// each other's latency -- r8's 9-wave WG could not pair on a CU (occupancy
// pinned at 24.5%), leaving ~0.9KB/CU of loads in flight vs ~9KB needed.
// SQ_LDS_BANK_CONFLICT ~5/b128 is intrinsic b128 overhead (constant across
// r6/r7/r8 with different write patterns) -- not a layout bug.

__global__ __launch_bounds__(192, 3)
void costvol_kernel(const float* __restrict__ x1,
                    const float* __restrict__ x2,
                    float* __restrict__ out)
{
  __shared__ float s2[2][CCH * SCH];   // 17,920 B

  const int t  = threadIdx.x;
  const int wv = t >> 6;               // 0..2
  const int l  = t & 63;
  const int h  = l & 7;
  const int m  = (l >> 3) & 1;
  const int c4 = l >> 4;

  const int tx = blockIdx.x;
  const int yy = blockIdx.y;           // type + 3*ty  (same-tile types are 8
  const int ty = yy / 3;               //  linear-ids apart -> same XCD/L2)
  const int tp = yy - 3 * ty;          // block type 0..2
  const int b  = blockIdx.z;
  const int x0 = tx * TW;
  const int y0 = ty * TH;

  const float* g1 = x1 + (size_t)b * Cn * HW + (size_t)(y0 + h) * Ww + (x0 + 8 * m);
  const float* g2 = x2 + (size_t)b * Cn * HW;

  // ---- float4-granular staging: slot j stages float4 f = t + 192*j ----
  int  soff[3], swr[3];
  bool sval[3], sok[3];
#pragma unroll
  for (int j = 0; j < 3; ++j) {
    const int f    = t + 192 * j;
    const bool okf = (f < NF4);
    const int ch   = f / (SRR * SC4);
    const int rem  = f % (SRR * SC4);
    const int row  = rem / SC4, col4 = rem % SC4;
    const int gy = y0 - HALO + 3 * tp + row;
    const int gx = x0 - HALO + 4 * col4;          // 16B-aligned granule
    const bool ok = okf && ((unsigned)gy < (unsigned)Hh) && ((unsigned)gx < (unsigned)Ww);
    sok[j]  = okf;
    sval[j] = ok;
    soff[j] = ok ? (ch * HW + gy * Ww + gx) : 0;
    swr[j]  = okf ? (ch * SCH + row * SS + 4 * col4) : 0;
  }

  float4 rs[3];
  auto stage_load = [&](int k) {
    const size_t cb = (size_t)(k * CCH) * HW;
#pragma unroll
    for (int j = 0; j < 3; ++j)
      rs[j] = sval[j] ? *reinterpret_cast<const float4*>(g2 + cb + soff[j])
                      : float4{0.f, 0.f, 0.f, 0.f};
  };
  auto stage_write = [&](int nb) {
    float* s = s2[nb];
#pragma unroll
    for (int j = 0; j < 3; ++j)
      if (sok[j]) *reinterpret_cast<float4*>(s + swr[j]) = rs[j];
  };

  // x1 loads for chunk k (both channel-steps), prefetched one chunk ahead
  auto x1_load = [&](int k, float4 a[4]) {
    const size_t c0 = (size_t)(CCH * k + c4) * HW;
    const size_t c1 = (size_t)(CCH * k + 4 + c4) * HW;
    a[0] = *reinterpret_cast<const float4*>(g1 + c0);
    a[1] = *reinterpret_cast<const float4*>(g1 + c0 + 4);
    a[2] = *reinterpret_cast<const float4*>(g1 + c1);
    a[3] = *reinterpret_cast<const float4*>(g1 + c1 + 4);
  };

  float acc[9][8];
#pragma unroll
  for (int d = 0; d < 9; ++d)
#pragma unroll
    for (int p = 0; p < 8; ++p) acc[d][p] = 0.0f;

  const int rbase = (h + wv) * SS + 8 * m;   // stage-relative window row

  float4 acur[4], anxt[4];
  x1_load(0, acur);
  stage_load(0);
  stage_write(0);
  __syncthreads();

  for (int k = 0; k < NCH; ++k) {
    if (k + 1 < NCH) {
      stage_load(k + 1);                 // issue early (T14)
      x1_load(k + 1, anxt);
    }
    const float* sc_ = s2[k & 1];
#pragma unroll
    for (int s = 0; s < 2; ++s) {
      const float* bp = sc_ + (4 * s + c4) * SCH + rbase;
      float w[16];
      *reinterpret_cast<float4*>(w)      = *reinterpret_cast<const float4*>(bp);
      *reinterpret_cast<float4*>(w + 4)  = *reinterpret_cast<const float4*>(bp + 4);
      *reinterpret_cast<float4*>(w + 8)  = *reinterpret_cast<const float4*>(bp + 8);
      *reinterpret_cast<float4*>(w + 12) = *reinterpret_cast<const float4*>(bp + 12);
      const float av[8] = {acur[2*s].x, acur[2*s].y, acur[2*s].z, acur[2*s].w,
                           acur[2*s+1].x, acur[2*s+1].y, acur[2*s+1].z, acur[2*s+1].w};
#pragma unroll
      for (int dj = 0; dj < 9; ++dj)
#pragma unroll
        for (int p = 0; p < 8; ++p)
          acc[dj][p] = fmaf(av[p], w[p + dj], acc[dj][p]);
    }
    if (k + 1 < NCH) {
      stage_write((k + 1) & 1);          // write late
#pragma unroll
      for (int q = 0; q < 4; ++q) acur[q] = anxt[q];
    }
    __syncthreads();
  }

  // ---- epilogue: reduce 4-way channel split (lanes l, l+16, l+32, l+48) ----
#pragma unroll
  for (int dj = 0; dj < 9; ++dj)
#pragma unroll
    for (int p = 0; p < 8; ++p) {
      float v = acc[dj][p];
      v += __shfl_down(v, 32);
      v += __shfl_down(v, 16);
      acc[dj][p] = v;
    }

  if (l < 16) {
    const float invc = 1.0f / (float)Cn;
    const int y  = y0 + h;
    const int xb = x0 + 8 * m;
    const int di = 3 * tp + wv;
#pragma unroll
    for (int dj = 0; dj < 9; ++dj) {
      const int o = di * 9 + dj;
      float* op = out + (((size_t)b * NOFF + o) * Hh + y) * Ww + xb;
      float4 v0, v1;
      v0.x = acc[dj][0] * invc; v0.y = acc[dj][1] * invc;
      v0.z = acc[dj][2] * invc; v0.w = acc[dj][3] * invc;
      v1.x = acc[dj][4] * invc; v1.y = acc[dj][5] * invc;
      v1.z = acc[dj][6] * invc; v1.w = acc[dj][7] * invc;
      *reinterpret_cast<float4*>(op)     = v0;
      *reinterpret_cast<float4*>(op + 4) = v1;
    }
  }
}

} // namespace

extern "C" void kernel_launch(void* const* d_in, const int* in_sizes, int n_in,
                              void* d_out, int out_size, void* d_ws, size_t ws_size,
                              hipStream_t stream) {
  const float* x1 = (const float*)d_in[0];
  const float* x2 = (const float*)d_in[1];
  float* out = (float*)d_out;

  // y encodes (type + 3*ty): sibling types of one tile are 8 linear-ids
  // apart -> same XCD -> shared x1/x2 tile data stays in that XCD's L2.
  dim3 grid(Ww / TW, 3 * (Hh / TH), 4);   // 8 x 48 x 4 = 1536 blocks
  dim3 block(192);                        // 3 waves: wave w <-> di = 3*type+w
  costvol_kernel<<<grid, block, 0, stream>>>(x1, x2, out);
}